// Round 7
// baseline (539.864 us; speedup 1.0000x reference)
//
#include <hip/hip_runtime.h>

#define N_NODES 8192
#define FDIM 128
#define NEG_SLOPE 0.2f

typedef short short8 __attribute__((ext_vector_type(8)));
typedef float floatx16 __attribute__((ext_vector_type(16)));
typedef unsigned long long u64;

__device__ inline unsigned fkey(float x) {
  unsigned b = __float_as_uint(x);
  return (b & 0x80000000u) ? ~b : (b | 0x80000000u);
}
__device__ inline float fkey_dec(unsigned kk) {
  unsigned bb = (kk & 0x80000000u) ? (kk ^ 0x80000000u) : ~kk;
  return __uint_as_float(bb);
}
__device__ inline unsigned short bf16_rn(float x) {
  unsigned u = __float_as_uint(x);
  u += 0x7fffu + ((u >> 16) & 1u);
  return (unsigned short)(u >> 16);
}

// ---- Kernel A (unchanged from R6, HW-verified): Wh=h@W.T; emits s1,
//      Bj=exp(s2), Dj=exp(.2 s2), s2max, Wh as bf16 hi/lo in B-frag order ----
__global__ __launch_bounds__(256) void wh_fused_kernel(
    const float* __restrict__ h, const float* __restrict__ W,
    const float* __restrict__ a, float* __restrict__ s1g,
    float* __restrict__ Bj, float* __restrict__ Dj,
    unsigned* __restrict__ s2max_key,
    unsigned short* __restrict__ Bfh, unsigned short* __restrict__ Bfl) {
  __shared__ float Wt[FDIM * 129];
  __shared__ float rows[32 * 132];
  const int t = threadIdx.x;
  const int base = blockIdx.x * 32;
  for (int it = 0; it < 64; ++it) {
    int idx = t + 256 * it;
    int o = idx >> 7, k = idx & 127;
    Wt[k * 129 + o] = W[idx];
  }
  for (int it = 0; it < 16; ++it) {
    int idx = t + 256 * it;
    int r = idx >> 7, col = idx & 127;
    rows[r * 132 + col] = h[(size_t)base * FDIM + idx];
  }
  __syncthreads();
  const int c4 = (t & 31) * 4;
  const int g = t >> 5;
  float acc[4][4];
#pragma unroll
  for (int rr = 0; rr < 4; ++rr)
#pragma unroll
    for (int cc = 0; cc < 4; ++cc) acc[rr][cc] = 0.f;
  for (int k = 0; k < FDIM; ++k) {
    float4 wv = *(const float4*)&Wt[k * 129 + c4];
    float rv[4];
#pragma unroll
    for (int rr = 0; rr < 4; ++rr) rv[rr] = rows[(4 * g + rr) * 132 + k];
#pragma unroll
    for (int rr = 0; rr < 4; ++rr) {
      acc[rr][0] += rv[rr] * wv.x;
      acc[rr][1] += rv[rr] * wv.y;
      acc[rr][2] += rv[rr] * wv.z;
      acc[rr][3] += rv[rr] * wv.w;
    }
  }
  {
    float4 a1c = *(const float4*)&a[c4];
    float4 a2c = *(const float4*)&a[FDIM + c4];
    float p1[4], p2[4];
#pragma unroll
    for (int rr = 0; rr < 4; ++rr) {
      p1[rr] = acc[rr][0] * a1c.x + acc[rr][1] * a1c.y +
               acc[rr][2] * a1c.z + acc[rr][3] * a1c.w;
      p2[rr] = acc[rr][0] * a2c.x + acc[rr][1] * a2c.y +
               acc[rr][2] * a2c.z + acc[rr][3] * a2c.w;
    }
#pragma unroll
    for (int rr = 0; rr < 4; ++rr)
      for (int off = 16; off; off >>= 1) {
        p1[rr] += __shfl_down(p1[rr], off, 32);
        p2[rr] += __shfl_down(p2[rr], off, 32);
      }
    if ((t & 31) == 0) {
      unsigned kmax = 0;
#pragma unroll
      for (int rr = 0; rr < 4; ++rr) {
        int r = base + 4 * g + rr;
        s1g[r] = p1[rr];
        Bj[r] = __expf(p2[rr]);
        Dj[r] = __expf(NEG_SLOPE * p2[rr]);
        unsigned kk = fkey(p2[rr]);
        kmax = kk > kmax ? kk : kmax;
      }
      atomicMax(s2max_key, kmax);
    }
  }
  __syncthreads();
  unsigned short* hbuf = (unsigned short*)Wt;
  unsigned short* lbuf = hbuf + 4096;
#pragma unroll
  for (int rr = 0; rr < 4; ++rr)
#pragma unroll
    for (int cc = 0; cc < 4; ++cc) {
      float x = acc[rr][cc];
      unsigned short hb = bf16_rn(x);
      float hf = __uint_as_float(((unsigned)hb) << 16);
      unsigned short lb = bf16_rn(x - hf);
      int lr = 4 * g + rr;
      int n = c4 + cc;
      int idx = (((lr >> 4) * 4 + (n >> 5)) * 64 + ((lr >> 3) & 1) * 32 +
                 (n & 31)) * 8 + (lr & 7);
      hbuf[idx] = hb;
      lbuf[idx] = lb;
    }
  __syncthreads();
  {
    const unsigned* hsrc = (const unsigned*)hbuf;
    const unsigned* lsrc = (const unsigned*)lbuf;
    unsigned* hdst = (unsigned*)(Bfh + (size_t)base * FDIM);
    unsigned* ldst = (unsigned*)(Bfl + (size_t)base * FDIM);
    for (int q = t; q < 2048; q += 256) { hdst[q] = hsrc[q]; ldst[q] = lsrc[q]; }
  }
}

// ---- Kernel B: block = 64 rows x 2048 K. Phase 1: coalesced adj tile ->
//      LDS bitmask (ballot-native layout). Phase 2: dense P@Wh via bf16
//      MFMA; A-frags generated from LDS bits + broadcast Bj/Dj; B hi/lo
//      from pre-packed global (L2). cred reduce via LDS fp32 atomics.
__global__ __launch_bounds__(256, 2) void gat_mfma_kernel(
    const float* __restrict__ adj,
    const unsigned short* __restrict__ Bfh,
    const unsigned short* __restrict__ Bfl,
    const float* __restrict__ s1g, const float* __restrict__ Bj,
    const float* __restrict__ Dj, const unsigned* __restrict__ s2max_key,
    float* __restrict__ num, float* __restrict__ l_ws) {
  __shared__ u64 bits_l[64 * 34];      // row stride 34 u64 (272 B): pad vs conflicts
  __shared__ float cred[64 * FDIM];    // 32 KB
  const int t = threadIdx.x;
  const int lane = t & 63;
  const int wave = t >> 6;
  const int rowgrp = blockIdx.x >> 2;
  const int ksplit = blockIdx.x & 3;
  const int grow0 = rowgrp * 64;
  const int blockK0 = ksplit * 2048;

  // ---- phase 1: wave w packs rows [16w,16w+16) x 2048 cols ----
  {
    const int rb = wave * 16;
    for (int rl = 0; rl < 16; ++rl) {
      const int r = rb + rl;
      const float4* src =
          (const float4*)(adj + (size_t)(grow0 + r) * N_NODES + blockK0);
      float4 va[8];
#pragma unroll
      for (int sg = 0; sg < 8; ++sg) va[sg] = src[sg * 64 + lane];
#pragma unroll
      for (int sg = 0; sg < 8; ++sg) {
        u64 b0 = __ballot(va[sg].x != 0.f);
        u64 b1 = __ballot(va[sg].y != 0.f);
        u64 b2 = __ballot(va[sg].z != 0.f);
        u64 b3 = __ballot(va[sg].w != 0.f);
        if (lane < 2) {
          u64 lo = lane ? b2 : b0;
          u64 hi = lane ? b3 : b1;
          u64* dst = &bits_l[r * 34 + sg * 4 + lane * 2];
          dst[0] = lo;
          dst[1] = hi;
        }
      }
    }
  }
  for (int q = t; q < 64 * FDIM; q += 256) cred[q] = 0.f;
  __syncthreads();

  // ---- per-row softmax constants (2 rows per lane) ----
  const int lq = lane & 31, hh = lane >> 5;
  const int gr0 = grow0 + lq, gr1 = gr0 + 32;
  const float s2m = fkey_dec(*s2max_key);
  const float s10 = s1g[gr0], s11 = s1g[gr1];
  float pm0 = s10 + s2m; pm0 = pm0 > 0.f ? pm0 : NEG_SLOPE * pm0;
  float pm1 = s11 + s2m; pm1 = pm1 > 0.f ? pm1 : NEG_SLOPE * pm1;
  const float m0 = fmaxf(pm0, 0.f), m1 = fmaxf(pm1, 0.f);
  const float em0 = __expf(-m0), em1 = __expf(-m1);
  const float Ai0 = __expf(s10 - m0), Ai1 = __expf(s11 - m1);
  const float Ci0 = __expf(NEG_SLOPE * s10 - m0), Ci1 = __expf(NEG_SLOPE * s11 - m1);
  const float Ti0 = __expf(-s10), Ti1 = __expf(-s11);

  const short8* BH = (const short8*)Bfh;
  const short8* BL = (const short8*)Bfl;
  floatx16 acc[2][4];
#pragma unroll
  for (int mt = 0; mt < 2; ++mt)
#pragma unroll
    for (int nt = 0; nt < 4; ++nt)
#pragma unroll
      for (int i = 0; i < 16; ++i) acc[mt][nt][i] = 0.f;
  float rsum0 = 0.f, rsum1 = 0.f;

  // ---- phase 2: wave handles segs {2w, 2w+1} (512 K) ----
  for (int s = 0; s < 2; ++s) {
    const int sg = wave * 2 + s;
    const u64* bp0 = &bits_l[lq * 34 + sg * 4];
    const u64* bp1 = &bits_l[(lq + 32) * 34 + sg * 4];
    longlong2 t0 = *(const longlong2*)bp0;
    longlong2 t1 = *(const longlong2*)(bp0 + 2);
    longlong2 t2 = *(const longlong2*)bp1;
    longlong2 t3 = *(const longlong2*)(bp1 + 2);
    u64 w0[4] = {(u64)t0.x, (u64)t0.y, (u64)t1.x, (u64)t1.y};
    u64 w1[4] = {(u64)t2.x, (u64)t2.y, (u64)t3.x, (u64)t3.y};
#pragma unroll 2
    for (int it = 0; it < 16; ++it) {
      const int kg = blockK0 + sg * 256 + it * 16;
      const int j8 = kg + hh * 8;
      float4 b0 = *(const float4*)(Bj + j8);
      float4 b1 = *(const float4*)(Bj + j8 + 4);
      float4 d0 = *(const float4*)(Dj + j8);
      float4 d1 = *(const float4*)(Dj + j8 + 4);
      size_t fb = ((size_t)(kg >> 4)) * 256 + lane;
      short8 xh0 = BH[fb],       xl0 = BL[fb];
      short8 xh1 = BH[fb + 64],  xl1 = BL[fb + 64];
      short8 xh2 = BH[fb + 128], xl2 = BL[fb + 128];
      short8 xh3 = BH[fb + 192], xl3 = BL[fb + 192];
      float bvv[8] = {b0.x, b0.y, b0.z, b0.w, b1.x, b1.y, b1.z, b1.w};
      float dvv[8] = {d0.x, d0.y, d0.z, d0.w, d1.x, d1.y, d1.z, d1.w};
      const int bsh = it * 4 + hh * 2;
      float pv0[8], pv1[8];
#pragma unroll
      for (int e = 0; e < 8; ++e) {
        const int sh = bsh + (e >> 2);
        float f0 = (float)((unsigned)(w0[e & 3] >> sh) & 1u);
        float f1 = (float)((unsigned)(w1[e & 3] >> sh) & 1u);
        bool cp0 = bvv[e] > Ti0, cp1 = bvv[e] > Ti1;
        float q0 = (cp0 ? Ai0 : Ci0) * (cp0 ? bvv[e] : dvv[e]);
        float q1 = (cp1 ? Ai1 : Ci1) * (cp1 ? bvv[e] : dvv[e]);
        float p0 = em0 + f0 * (q0 - em0);
        float p1 = em1 + f1 * (q1 - em1);
        rsum0 += p0; rsum1 += p1;
        pv0[e] = p0; pv1[e] = p1;
      }
      union { uint4 u; short8 s8; } k0, k1;
      k0.u.x = (unsigned)bf16_rn(pv0[0]) | ((unsigned)bf16_rn(pv0[1]) << 16);
      k0.u.y = (unsigned)bf16_rn(pv0[2]) | ((unsigned)bf16_rn(pv0[3]) << 16);
      k0.u.z = (unsigned)bf16_rn(pv0[4]) | ((unsigned)bf16_rn(pv0[5]) << 16);
      k0.u.w = (unsigned)bf16_rn(pv0[6]) | ((unsigned)bf16_rn(pv0[7]) << 16);
      k1.u.x = (unsigned)bf16_rn(pv1[0]) | ((unsigned)bf16_rn(pv1[1]) << 16);
      k1.u.y = (unsigned)bf16_rn(pv1[2]) | ((unsigned)bf16_rn(pv1[3]) << 16);
      k1.u.z = (unsigned)bf16_rn(pv1[4]) | ((unsigned)bf16_rn(pv1[5]) << 16);
      k1.u.w = (unsigned)bf16_rn(pv1[6]) | ((unsigned)bf16_rn(pv1[7]) << 16);
      short8 af0 = k0.s8, af1 = k1.s8;
      acc[0][0] = __builtin_amdgcn_mfma_f32_32x32x16_bf16(af0, xh0, acc[0][0], 0, 0, 0);
      acc[0][0] = __builtin_amdgcn_mfma_f32_32x32x16_bf16(af0, xl0, acc[0][0], 0, 0, 0);
      acc[0][1] = __builtin_amdgcn_mfma_f32_32x32x16_bf16(af0, xh1, acc[0][1], 0, 0, 0);
      acc[0][1] = __builtin_amdgcn_mfma_f32_32x32x16_bf16(af0, xl1, acc[0][1], 0, 0, 0);
      acc[0][2] = __builtin_amdgcn_mfma_f32_32x32x16_bf16(af0, xh2, acc[0][2], 0, 0, 0);
      acc[0][2] = __builtin_amdgcn_mfma_f32_32x32x16_bf16(af0, xl2, acc[0][2], 0, 0, 0);
      acc[0][3] = __builtin_amdgcn_mfma_f32_32x32x16_bf16(af0, xh3, acc[0][3], 0, 0, 0);
      acc[0][3] = __builtin_amdgcn_mfma_f32_32x32x16_bf16(af0, xl3, acc[0][3], 0, 0, 0);
      acc[1][0] = __builtin_amdgcn_mfma_f32_32x32x16_bf16(af1, xh0, acc[1][0], 0, 0, 0);
      acc[1][0] = __builtin_amdgcn_mfma_f32_32x32x16_bf16(af1, xl0, acc[1][0], 0, 0, 0);
      acc[1][1] = __builtin_amdgcn_mfma_f32_32x32x16_bf16(af1, xh1, acc[1][1], 0, 0, 0);
      acc[1][1] = __builtin_amdgcn_mfma_f32_32x32x16_bf16(af1, xl1, acc[1][1], 0, 0, 0);
      acc[1][2] = __builtin_amdgcn_mfma_f32_32x32x16_bf16(af1, xh2, acc[1][2], 0, 0, 0);
      acc[1][2] = __builtin_amdgcn_mfma_f32_32x32x16_bf16(af1, xl2, acc[1][2], 0, 0, 0);
      acc[1][3] = __builtin_amdgcn_mfma_f32_32x32x16_bf16(af1, xh3, acc[1][3], 0, 0, 0);
      acc[1][3] = __builtin_amdgcn_mfma_f32_32x32x16_bf16(af1, xl3, acc[1][3], 0, 0, 0);
    }
  }

  // ---- l partials ----
  rsum0 += __shfl_xor(rsum0, 32);
  rsum1 += __shfl_xor(rsum1, 32);
  if (lane < 32) {
    atomicAdd(&l_ws[gr0], rsum0);
    atomicAdd(&l_ws[gr1], rsum1);
  }

  // ---- cred: LDS fp32 atomics (C layout: col=lane&31,
  //      row=(reg&3)+8*(reg>>2)+4*hh — verified R6) ----
#pragma unroll
  for (int reg = 0; reg < 16; ++reg) {
    const int r = (reg & 3) + 8 * (reg >> 2) + 4 * hh;
#pragma unroll
    for (int nt = 0; nt < 4; ++nt) {
      atomicAdd(&cred[r * FDIM + nt * 32 + lq], acc[0][nt][reg]);
      atomicAdd(&cred[(r + 32) * FDIM + nt * 32 + lq], acc[1][nt][reg]);
    }
  }
  __syncthreads();
#pragma unroll
  for (int q = 0; q < 32; ++q) {
    const int idx = q * 256 + t;
    atomicAdd(&num[(size_t)(grow0 + (idx >> 7)) * FDIM + (idx & 127)],
              cred[idx]);
  }
}

// ---- Kernel C: out = num / l ----
__global__ __launch_bounds__(256) void norm_kernel(
    const float* __restrict__ num, const float* __restrict__ l_ws,
    float* __restrict__ out) {
  int idx = blockIdx.x * 256 + threadIdx.x;
  float4 v = ((const float4*)num)[idx];
  float li = l_ws[idx >> 5];
  ((float4*)out)[idx] = make_float4(v.x / li, v.y / li, v.z / li, v.w / li);
}

extern "C" void kernel_launch(void* const* d_in, const int* in_sizes, int n_in,
                              void* d_out, int out_size, void* d_ws, size_t ws_size,
                              hipStream_t stream) {
  const float* h   = (const float*)d_in[0];
  const float* adj = (const float*)d_in[1];
  const float* W   = (const float*)d_in[2];
  const float* a   = (const float*)d_in[3];
  float* out = (float*)d_out;
  // ws (8.5 MB): num[1048576] | l[8192] | key[1] | s1[8192] | Bj[8192]
  //              | Dj[8192] | Bfh[1M u16] | Bfl[1M u16]
  float* num = (float*)d_ws;
  float* l_ws = num + (size_t)N_NODES * FDIM;
  unsigned* key = (unsigned*)(l_ws + N_NODES);
  float* s1 = (float*)(key + 1);
  float* Bj = s1 + N_NODES;
  float* Dj = Bj + N_NODES;
  unsigned short* Bfh = (unsigned short*)(Dj + N_NODES);
  unsigned short* Bfl = Bfh + (size_t)N_NODES * FDIM;

  hipMemsetAsync(num, 0, ((size_t)N_NODES * FDIM + N_NODES + 1) * sizeof(float),
                 stream);
  hipLaunchKernelGGL(wh_fused_kernel, dim3(N_NODES / 32), dim3(256), 0, stream,
                     h, W, a, s1, Bj, Dj, key, Bfh, Bfl);
  hipLaunchKernelGGL(gat_mfma_kernel, dim3(512), dim3(256), 0, stream,
                     adj, Bfh, Bfl, s1, Bj, Dj, key, num, l_ws);
  hipLaunchKernelGGL(norm_kernel, dim3(N_NODES * FDIM / 4 / 256), dim3(256), 0,
                     stream, num, l_ws, out);
}

// Round 8
// 490.181 us; speedup vs baseline: 1.1014x; 1.1014x over previous
//
#include <hip/hip_runtime.h>

#define N_NODES 8192
#define FDIM 128
#define NEG_SLOPE 0.2f

typedef short short8 __attribute__((ext_vector_type(8)));
typedef float floatx16 __attribute__((ext_vector_type(16)));
typedef unsigned long long u64;

static __device__ inline unsigned fkey(float x) {
  unsigned b = __float_as_uint(x);
  return (b & 0x80000000u) ? ~b : (b | 0x80000000u);
}
static __device__ inline float fkey_dec(unsigned kk) {
  unsigned bb = (kk & 0x80000000u) ? (kk ^ 0x80000000u) : ~kk;
  return __uint_as_float(bb);
}
static __device__ inline unsigned short bf16_rn(float x) {
  unsigned u = __float_as_uint(x);
  u += 0x7fffu + ((u >> 16) & 1u);
  return (unsigned short)(u >> 16);
}

// ---- Kernel A: Wh=h@W.T; emits s1, Bj=exp(s2), Dj=exp(.2 s2), s2max,
//      S=colsum(Wh) fp32, and Wh as bf16 in MFMA-B-fragment order. ----
__global__ __launch_bounds__(256) void wh_fused_kernel(
    const float* __restrict__ h, const float* __restrict__ W,
    const float* __restrict__ a, float* __restrict__ s1g,
    float* __restrict__ Bj, float* __restrict__ Dj, float* __restrict__ S,
    unsigned* __restrict__ s2max_key, unsigned short* __restrict__ WHf) {
  __shared__ float Wt[FDIM * 129];
  __shared__ float rows[32 * 132];
  const int t = threadIdx.x;
  const int base = blockIdx.x * 32;
  for (int it = 0; it < 64; ++it) {
    int idx = t + 256 * it;
    int o = idx >> 7, k = idx & 127;
    Wt[k * 129 + o] = W[idx];
  }
  for (int it = 0; it < 16; ++it) {
    int idx = t + 256 * it;
    int r = idx >> 7, col = idx & 127;
    rows[r * 132 + col] = h[(size_t)base * FDIM + idx];
  }
  __syncthreads();
  const int c4 = (t & 31) * 4;
  const int g = t >> 5;
  float acc[4][4];
#pragma unroll
  for (int rr = 0; rr < 4; ++rr)
#pragma unroll
    for (int cc = 0; cc < 4; ++cc) acc[rr][cc] = 0.f;
  for (int k = 0; k < FDIM; ++k) {
    float4 wv = *(const float4*)&Wt[k * 129 + c4];
    float rv[4];
#pragma unroll
    for (int rr = 0; rr < 4; ++rr) rv[rr] = rows[(4 * g + rr) * 132 + k];
#pragma unroll
    for (int rr = 0; rr < 4; ++rr) {
      acc[rr][0] += rv[rr] * wv.x;
      acc[rr][1] += rv[rr] * wv.y;
      acc[rr][2] += rv[rr] * wv.z;
      acc[rr][3] += rv[rr] * wv.w;
    }
  }
  // ---- s1/s2 epilogue (verified R6/R7) ----
  {
    float4 a1c = *(const float4*)&a[c4];
    float4 a2c = *(const float4*)&a[FDIM + c4];
    float p1[4], p2[4];
#pragma unroll
    for (int rr = 0; rr < 4; ++rr) {
      p1[rr] = acc[rr][0] * a1c.x + acc[rr][1] * a1c.y +
               acc[rr][2] * a1c.z + acc[rr][3] * a1c.w;
      p2[rr] = acc[rr][0] * a2c.x + acc[rr][1] * a2c.y +
               acc[rr][2] * a2c.z + acc[rr][3] * a2c.w;
    }
#pragma unroll
    for (int rr = 0; rr < 4; ++rr)
      for (int off = 16; off; off >>= 1) {
        p1[rr] += __shfl_down(p1[rr], off, 32);
        p2[rr] += __shfl_down(p2[rr], off, 32);
      }
    if ((t & 31) == 0) {
      unsigned kmax = 0;
#pragma unroll
      for (int rr = 0; rr < 4; ++rr) {
        int r = base + 4 * g + rr;
        s1g[r] = p1[rr];
        Bj[r] = __expf(p2[rr]);
        Dj[r] = __expf(NEG_SLOPE * p2[rr]);
        unsigned kk = fkey(p2[rr]);
        kmax = kk > kmax ? kk : kmax;
      }
      atomicMax(s2max_key, kmax);
    }
  }
  // ---- repack acc -> bf16 B-fragment order (Wt as scratch) + colsum ----
  __syncthreads();
  unsigned short* hbuf = (unsigned short*)Wt;
#pragma unroll
  for (int rr = 0; rr < 4; ++rr)
#pragma unroll
    for (int cc = 0; cc < 4; ++cc) {
      int lr = 4 * g + rr;
      int n = c4 + cc;
      int idx = (((lr >> 4) * 4 + (n >> 5)) * 64 + ((lr >> 3) & 1) * 32 +
                 (n & 31)) * 8 + (lr & 7);
      hbuf[idx] = bf16_rn(acc[rr][cc]);
    }
  float4 cs = make_float4(acc[0][0] + acc[1][0] + acc[2][0] + acc[3][0],
                          acc[0][1] + acc[1][1] + acc[2][1] + acc[3][1],
                          acc[0][2] + acc[1][2] + acc[2][2] + acc[3][2],
                          acc[0][3] + acc[1][3] + acc[2][3] + acc[3][3]);
  *(float4*)&rows[g * FDIM + c4] = cs;
  __syncthreads();
  {
    const unsigned* hsrc = (const unsigned*)hbuf;
    unsigned* hdst = (unsigned*)(WHf + (size_t)base * FDIM);
    for (int q = t; q < 2048; q += 256) hdst[q] = hsrc[q];
  }
  if (t < FDIM) {
    float s = 0.f;
#pragma unroll
    for (int gg = 0; gg < 8; ++gg) s += rows[gg * FDIM + t];
    atomicAdd(&S[t], s);
  }
}

// ---- Kernel B: barrier-free fused scan + V@Wh MFMA. Block = 32 rows x
//      2048 K (4 waves x 512 K each, private). Per 256-col subtile a wave:
//      (1) loads its 32x256 adj window coalesced, ballot-packs bits into
//          its PRIVATE LDS strip (same-wave DS order, no barrier);
//      (2) 16 k16-iters: A-frag = v_ik = mask*(q - em) generated in-regs
//          (q = A_i*Bj or C_i*Dj, all precomputed), B = plain bf16 Wh.
//      num = V@Wh (+ em*S in norm); l = N*em + rowsum(v).
__global__ __launch_bounds__(256) void gat_mfma_kernel(
    const float* __restrict__ adj, const unsigned short* __restrict__ WHf,
    const float* __restrict__ s1g, const float* __restrict__ Bj,
    const float* __restrict__ Dj, const unsigned* __restrict__ s2max_key,
    float* __restrict__ num, float* __restrict__ l_ws) {
  __shared__ u64 bits[4][32][4];     // [wave][row][ballot-quad]
  __shared__ float cred[32 * FDIM];  // 16 KB
  const int t = threadIdx.x;
  const int lane = t & 63;
  const int wave = t >> 6;
  const int lq = lane & 31, hh = lane >> 5;
  const int rowgrp = blockIdx.x >> 2;
  const int ksplit = blockIdx.x & 3;
  const int grow = rowgrp * 32;
  const int kw0 = ksplit * 2048 + wave * 512;

  for (int q = t; q < 32 * FDIM; q += 256) cred[q] = 0.f;
  __syncthreads();  // cred zeroed before any wave's epilogue atomics

  // per-row (lane) softmax constants; m_i = max(0, lrelu(s1_i+s2max))
  const float s2m = fkey_dec(*s2max_key);
  const float s1r = s1g[grow + lq];
  float pm = s1r + s2m;
  pm = pm > 0.f ? pm : NEG_SLOPE * pm;
  const float mr = fmaxf(pm, 0.f);
  const float emr = __expf(-mr);
  const float Ar = __expf(s1r - mr);
  const float Cr = __expf(NEG_SLOPE * s1r - mr);
  const float Tr = __expf(-s1r);  // cp: s1+s2>0 <=> Bj > Tr

  const short8* BW = (const short8*)WHf;
  floatx16 acc[4];
#pragma unroll
  for (int nt = 0; nt < 4; ++nt)
#pragma unroll
    for (int i = 0; i < 16; ++i) acc[nt][i] = 0.f;
  float lv = 0.f;
  u64* mybits = &bits[wave][0][0];

  for (int s = 0; s < 2; ++s) {
    const int c0 = kw0 + s * 256;
    const float4* ap = (const float4*)(adj + (size_t)grow * N_NODES + c0);
    // ---- pack: 32 rows x 256 cols, batches of 8 rows ----
#pragma unroll 2
    for (int rb = 0; rb < 32; rb += 8) {
      float4 va[8];
#pragma unroll
      for (int r = 0; r < 8; ++r)
        va[r] = ap[(size_t)(rb + r) * (N_NODES / 4) + lane];
#pragma unroll
      for (int r = 0; r < 8; ++r) {
        u64 b0 = __ballot(va[r].x != 0.f);
        u64 b1 = __ballot(va[r].y != 0.f);
        u64 b2 = __ballot(va[r].z != 0.f);
        u64 b3 = __ballot(va[r].w != 0.f);
        if (lane == 0) {
          u64* d = &mybits[(rb + r) * 4];
          d[0] = b0; d[1] = b1; d[2] = b2; d[3] = b3;
        }
      }
    }
    // ---- own-row bits (same-wave DS ordering; compiler emits lgkmcnt) ----
    ulonglong2 q0 = *(const ulonglong2*)&mybits[lq * 4];
    ulonglong2 q1 = *(const ulonglong2*)&mybits[lq * 4 + 2];
    const u64 ws0 = q0.x, ws1 = q0.y, ws2 = q1.x, ws3 = q1.y;
    // ---- 16 MFMA iters over this 256-col window ----
#pragma unroll 2
    for (int it = 0; it < 16; ++it) {
      const int kg = c0 + it * 16;
      const int j8 = kg + hh * 8;
      float4 b0 = *(const float4*)(Bj + j8);
      float4 b1 = *(const float4*)(Bj + j8 + 4);
      float4 d0 = *(const float4*)(Dj + j8);
      float4 d1 = *(const float4*)(Dj + j8 + 4);
      size_t fb = (size_t)(kg >> 4) * 256 + lane;
      short8 x0 = BW[fb];
      short8 x1 = BW[fb + 64];
      short8 x2 = BW[fb + 128];
      short8 x3 = BW[fb + 192];
      float bvv[8] = {b0.x, b0.y, b0.z, b0.w, b1.x, b1.y, b1.z, b1.w};
      float dvv[8] = {d0.x, d0.y, d0.z, d0.w, d1.x, d1.y, d1.z, d1.w};
      const u64 wsel[4] = {ws0, ws1, ws2, ws3};
      const int bsh = it * 4 + hh * 2;
      float vv[8];
#pragma unroll
      for (int e = 0; e < 8; ++e) {
        unsigned bit = (unsigned)(wsel[e & 3] >> (bsh + (e >> 2))) & 1u;
        bool cp = bvv[e] > Tr;
        float q = (cp ? Ar : Cr) * (cp ? bvv[e] : dvv[e]);
        float v = bit ? (q - emr) : 0.f;
        vv[e] = v;
        lv += v;
      }
      union { uint4 u; short8 s8; } pk;
      pk.u.x = (unsigned)bf16_rn(vv[0]) | ((unsigned)bf16_rn(vv[1]) << 16);
      pk.u.y = (unsigned)bf16_rn(vv[2]) | ((unsigned)bf16_rn(vv[3]) << 16);
      pk.u.z = (unsigned)bf16_rn(vv[4]) | ((unsigned)bf16_rn(vv[5]) << 16);
      pk.u.w = (unsigned)bf16_rn(vv[6]) | ((unsigned)bf16_rn(vv[7]) << 16);
      short8 af = pk.s8;
      acc[0] = __builtin_amdgcn_mfma_f32_32x32x16_bf16(af, x0, acc[0], 0, 0, 0);
      acc[1] = __builtin_amdgcn_mfma_f32_32x32x16_bf16(af, x1, acc[1], 0, 0, 0);
      acc[2] = __builtin_amdgcn_mfma_f32_32x32x16_bf16(af, x2, acc[2], 0, 0, 0);
      acc[3] = __builtin_amdgcn_mfma_f32_32x32x16_bf16(af, x3, acc[3], 0, 0, 0);
    }
  }
  // ---- l partials: halves hold same row, disjoint k ----
  float lvt = lv + __shfl_xor(lv, 32);
  if (lane < 32) atomicAdd(&l_ws[grow + lq], lvt);
  // ---- C tiles -> cred (LDS f32 atomics); layout verified R6/R7:
  //      col = nt*32 + lq, row = (reg&3) + 8*(reg>>2) + 4*hh ----
#pragma unroll
  for (int reg = 0; reg < 16; ++reg) {
    const int r = (reg & 3) + 8 * (reg >> 2) + 4 * hh;
#pragma unroll
    for (int nt = 0; nt < 4; ++nt)
      atomicAdd(&cred[r * FDIM + nt * 32 + lq], acc[nt][reg]);
  }
  __syncthreads();
  for (int q = t; q < 32 * FDIM; q += 256)
    atomicAdd(&num[(size_t)(grow + (q >> 7)) * FDIM + (q & 127)], cred[q]);
}

// ---- Kernel C: out = (num + em*S) / (N*em + l_ws) ----
__global__ __launch_bounds__(256) void norm_kernel(
    const float* __restrict__ num, const float* __restrict__ l_ws,
    const float* __restrict__ s1g, const unsigned* __restrict__ s2max_key,
    const float* __restrict__ S, float* __restrict__ out) {
  const int idx = blockIdx.x * 256 + threadIdx.x;  // float4 index
  const int row = idx >> 5;
  const float s2m = fkey_dec(*s2max_key);
  float s1r = s1g[row];
  float pm = s1r + s2m;
  pm = pm > 0.f ? pm : NEG_SLOPE * pm;
  float mr = fmaxf(pm, 0.f);
  float em = __expf(-mr);
  float l = (float)N_NODES * em + l_ws[row];
  float inv = 1.f / l;
  float4 nv = ((const float4*)num)[idx];
  float4 Sv = ((const float4*)S)[idx & 31];
  ((float4*)out)[idx] = make_float4((nv.x + em * Sv.x) * inv,
                                    (nv.y + em * Sv.y) * inv,
                                    (nv.z + em * Sv.z) * inv,
                                    (nv.w + em * Sv.w) * inv);
}

extern "C" void kernel_launch(void* const* d_in, const int* in_sizes, int n_in,
                              void* d_out, int out_size, void* d_ws, size_t ws_size,
                              hipStream_t stream) {
  const float* h   = (const float*)d_in[0];
  const float* adj = (const float*)d_in[1];
  const float* W   = (const float*)d_in[2];
  const float* a   = (const float*)d_in[3];
  float* out = (float*)d_out;
  // ws (~6.2 MB): num[1M f] | l[8K f] | S[128 f] | key[4 u32] | s1[8K f]
  //               | Bj[8K f] | Dj[8K f] | WHf[1M u16]
  float* num = (float*)d_ws;
  float* l_ws = num + (size_t)N_NODES * FDIM;
  float* S = l_ws + N_NODES;
  unsigned* key = (unsigned*)(S + FDIM);
  float* s1 = (float*)(key + 4);
  float* Bj = s1 + N_NODES;
  float* Dj = Bj + N_NODES;
  unsigned short* WHf = (unsigned short*)(Dj + N_NODES);

  hipMemsetAsync(num, 0,
                 ((size_t)N_NODES * FDIM + N_NODES + FDIM + 4) * sizeof(float),
                 stream);
  hipLaunchKernelGGL(wh_fused_kernel, dim3(N_NODES / 32), dim3(256), 0, stream,
                     h, W, a, s1, Bj, Dj, S, key, WHf);
  hipLaunchKernelGGL(gat_mfma_kernel, dim3(1024), dim3(256), 0, stream,
                     adj, WHf, s1, Bj, Dj, key, num, l_ws);
  hipLaunchKernelGGL(norm_kernel, dim3(N_NODES * FDIM / 4 / 256), dim3(256), 0,
                     stream, num, l_ws, s1, key, S, out);
}